// Round 12
// baseline (436.878 us; speedup 1.0000x reference)
//
#include <hip/hip_runtime.h>
#include <hip/hip_bf16.h>
#include <math.h>

// ---------------------------------------------------------------------------
// GAT 3-layer forward.
// R12: (1) agg4/agg16 phase-3 accumulation as float2 -> v_pk_fma_f32 dual
// FMA (agg4 is the only VALU>50% dispatch); (2) gemm_mfma featb epilogue
// packs col-pairs via shfl_xor(1) -> 32 dword stores instead of 64 short
// stores; (3) wcvt/acvt prep merged into one ranged kernel.
// Pipeline unchanged otherwise: f16 single-term MFMA GEMM + fused elr,
// bf16 featb gather operand, f16 inter-layer activations.
// ---------------------------------------------------------------------------

#define NEG_SLOPE 0.2f

typedef __attribute__((ext_vector_type(8))) _Float16 v8h;  // 8 f16 in 4 VGPRs
typedef __attribute__((ext_vector_type(4))) float f32x4;

__device__ __forceinline__ float2 fma2(float2 a, float2 b, float2 c) {
    return make_float2(fmaf(a.x, b.x, c.x), fmaf(a.y, b.y, c.y));
}

// ---------------- CSR build ----------------

__global__ __launch_bounds__(256) void count_deg(const int* __restrict__ dst,
                                                 int* __restrict__ deg, int E) {
    int e = blockIdx.x * 256 + threadIdx.x;
    if (e < E) atomicAdd(&deg[dst[e]], 1);
}

__global__ __launch_bounds__(256) void scan_chunk(int* __restrict__ off,
                                                  int* __restrict__ chunkSum, int N) {
    __shared__ int sdata[256];
    int tid = threadIdx.x;
    int base = blockIdx.x * 2048 + tid * 8;
    int v[8];
    int tsum = 0;
#pragma unroll
    for (int j = 0; j < 8; ++j) {
        int idx = base + j;
        v[j] = (idx < N) ? off[idx] : 0;
        tsum += v[j];
    }
    sdata[tid] = tsum;
    __syncthreads();
    for (int o = 1; o < 256; o <<= 1) {
        int t = (tid >= o) ? sdata[tid - o] : 0;
        __syncthreads();
        sdata[tid] += t;
        __syncthreads();
    }
    int run = sdata[tid] - tsum;
#pragma unroll
    for (int j = 0; j < 8; ++j) {
        int idx = base + j;
        if (idx < N) off[idx] = run;
        run += v[j];
    }
    if (tid == 255) chunkSum[blockIdx.x] = sdata[255];
}

__global__ void scan_tail(const int* __restrict__ chunkSum, int* __restrict__ chunkOff,
                          int nchunks, int* __restrict__ off, int N, int E) {
    if (threadIdx.x == 0 && blockIdx.x == 0) {
        int run = 0;
        for (int c = 0; c < nchunks; ++c) { chunkOff[c] = run; run += chunkSum[c]; }
        off[N] = E;
    }
}

__global__ __launch_bounds__(256) void add_chunk_off(int* __restrict__ off,
                                                     int* __restrict__ cursor,
                                                     const int* __restrict__ chunkOff, int N) {
    int i = blockIdx.x * 256 + threadIdx.x;
    if (i < N) {
        int v = off[i] + chunkOff[i >> 11];
        off[i] = v;
        cursor[i] = v;
    }
}

__global__ __launch_bounds__(256) void scatter_edges(const int* __restrict__ src,
                                                     const int* __restrict__ dst,
                                                     int* __restrict__ cursor,
                                                     int* __restrict__ csr, int E) {
    int e = blockIdx.x * 256 + threadIdx.x;
    if (e < E) {
        int d = dst[e];
        int pos = atomicAdd(&cursor[d], 1);
        csr[pos] = src[e];
    }
}

// ---------------- f16 helpers ----------------

__device__ __forceinline__ unsigned short bf16_rne(float x) {
    unsigned int u = __float_as_uint(x);
    return (unsigned short)((u + 0x7fffu + ((u >> 16) & 1u)) >> 16);
}

__device__ __forceinline__ unsigned short f16_bits(float x) {
    _Float16 h = (_Float16)x;
    union { _Float16 h; unsigned short u; } c;
    c.h = h;
    return c.u;
}

__device__ __forceinline__ float f16_to_f32(unsigned short u) {
    union { _Float16 h; unsigned short u; } c;
    c.u = u;
    return (float)c.h;
}

// Fused prep: inputs -> a0f (f16 stream, 4/thread), W0/W1 -> f16 transposed.
__global__ __launch_bounds__(256) void prep_cvt(const float* __restrict__ inputs,
                                                const float* __restrict__ W0,
                                                const float* __restrict__ W1,
                                                unsigned short* __restrict__ a0f,
                                                unsigned short* __restrict__ wt0,
                                                unsigned short* __restrict__ wt1,
                                                int nA4) {
    int i = blockIdx.x * 256 + threadIdx.x;
    if (i < nA4) {
        float4 v = *(const float4*)&inputs[(size_t)i * 4];
        *(ushort4*)&a0f[(size_t)i * 4] = make_ushort4(f16_bits(v.x), f16_bits(v.y),
                                                      f16_bits(v.z), f16_bits(v.w));
        return;
    }
    int j = i - nA4;
    if (j < 128 * 256) {  // W0: [128][256] -> wt0 [256][128]
        int f = j >> 8, k = j & 255;
        wt0[k * 128 + f] = f16_bits(W0[j]);
        return;
    }
    j -= 128 * 256;
    if (j < 256 * 256) {  // W1: [256][256] -> wt1 [256][256]
        int f = j >> 8, k = j & 255;
        wt1[k * 256 + f] = f16_bits(W1[j]);
    }
}

// ---------------- f16 MFMA GEMM fused with el/er + bf16 featb -------------

__global__ __launch_bounds__(256) void gemm_mfma(const unsigned short* __restrict__ Af,
                                                 const unsigned short* __restrict__ Bt,
                                                 unsigned short* __restrict__ featb,
                                                 float* __restrict__ el,
                                                 float* __restrict__ er,
                                                 const float* __restrict__ al,
                                                 const float* __restrict__ ar,
                                                 int N, int F, int K) {
    __shared__ unsigned short As[128][40];
    __shared__ unsigned short Bs[128][40];
    int tid = threadIdx.x;
    int lane = tid & 63, w = tid >> 6;
    int wr = (w >> 1) * 64, wc = (w & 1) * 64;
    int lr = lane & 15, lq = lane >> 4;
    int m0 = blockIdx.y * 128, n0 = blockIdx.x * 128;
    f32x4 acc[4][4] = {};

    for (int k0 = 0; k0 < F; k0 += 32) {
        __syncthreads();
#pragma unroll
        for (int i = 0; i < 2; ++i) {
            int slot = i * 256 + tid;
            int r = slot >> 2, cc = slot & 3;
            uint4 v = make_uint4(0u, 0u, 0u, 0u);
            int gr = m0 + r;
            if (gr < N) v = *(const uint4*)&Af[(size_t)gr * F + k0 + cc * 8];
            *(uint4*)&As[r][cc * 8] = v;
        }
#pragma unroll
        for (int i = 0; i < 2; ++i) {
            int slot = i * 256 + tid;
            int r = slot >> 2, cc = slot & 3;
            uint4 bv = *(const uint4*)&Bt[(size_t)(n0 + r) * F + k0 + cc * 8];
            *(uint4*)&Bs[r][cc * 8] = bv;
        }
        __syncthreads();

        v8h af[4], bf[4];
#pragma unroll
        for (int mt = 0; mt < 4; ++mt)
            af[mt] = *(const v8h*)&As[wr + mt * 16 + lr][lq * 8];
#pragma unroll
        for (int nt = 0; nt < 4; ++nt)
            bf[nt] = *(const v8h*)&Bs[wc + nt * 16 + lr][lq * 8];
#pragma unroll
        for (int mt = 0; mt < 4; ++mt)
#pragma unroll
            for (int nt = 0; nt < 4; ++nt)
                acc[mt][nt] = __builtin_amdgcn_mfma_f32_16x16x32_f16(af[mt], bf[nt], acc[mt][nt], 0, 0, 0);
    }

    int h = (n0 + wc) >> 6;
    float alw[4], arw[4];
#pragma unroll
    for (int nt = 0; nt < 4; ++nt) {
        int d = nt * 16 + lr;
        alw[nt] = al[h * 64 + d];
        arw[nt] = ar[h * 64 + d];
    }
#pragma unroll
    for (int mt = 0; mt < 4; ++mt) {
#pragma unroll
        for (int r = 0; r < 4; ++r) {
            float se = 0.f, sr = 0.f;
#pragma unroll
            for (int nt = 0; nt < 4; ++nt) {
                float v = acc[mt][nt][r];
                se += v * alw[nt];
                sr += v * arw[nt];
            }
#pragma unroll
            for (int o = 8; o >= 1; o >>= 1) {
                se += __shfl_xor(se, o);
                sr += __shfl_xor(sr, o);
            }
            int row = m0 + wr + mt * 16 + lq * 4 + r;
            if (lr == 0 && row < N) {
                el[(size_t)row * 4 + h] = se;
                er[(size_t)row * 4 + h] = sr;
            }
        }
    }
    // featb store: pack col-pairs via shfl_xor(1) -> dword stores (even lr)
#pragma unroll
    for (int mt = 0; mt < 4; ++mt) {
#pragma unroll
        for (int nt = 0; nt < 4; ++nt) {
            int col = n0 + wc + nt * 16 + lr;
#pragma unroll
            for (int r = 0; r < 4; ++r) {
                int row = m0 + wr + mt * 16 + lq * 4 + r;
                unsigned int me = (unsigned int)bf16_rne(acc[mt][nt][r]);
                unsigned int nb = (unsigned int)__shfl_xor((int)me, 1);
                if (!(lr & 1) && row < N) {
                    unsigned int pk = me | (nb << 16);
                    *(unsigned int*)&featb[(size_t)row * K + col] = pk;
                }
            }
        }
    }
}

// ---------------- fp32 GEMM (layer 2, K=16) fused with el/er + bf16 ------

__global__ __launch_bounds__(256) void gemm_kernel(const unsigned short* __restrict__ Af,
                                                   const float* __restrict__ W,
                                                   const float* __restrict__ al2,
                                                   const float* __restrict__ ar2,
                                                   float* __restrict__ el,
                                                   float* __restrict__ er,
                                                   unsigned short* __restrict__ featb,
                                                   int N, int F, int K) {
    __shared__ __align__(16) float As2[16][68];
    __shared__ __align__(16) float Ws2[16][64];
    int tid = threadIdx.x;
    int tx = tid & 15, ty = tid >> 4;
    int r0 = blockIdx.y * 64;
    int arow = tid >> 2, akq = tid & 3;
    int wk = tid >> 4, wcq = tid & 15;
    float acc[4][4] = {};

    for (int k0 = 0; k0 < F; k0 += 16) {
        float4 av = make_float4(0.f, 0.f, 0.f, 0.f);
        int gr = r0 + arow;
        if (gr < N) {
            size_t base = (size_t)gr * F + k0 + akq * 4;
            uint2 vh = *(const uint2*)&Af[base];
            av.x = f16_to_f32((unsigned short)(vh.x & 0xffffu));
            av.y = f16_to_f32((unsigned short)(vh.x >> 16));
            av.z = f16_to_f32((unsigned short)(vh.y & 0xffffu));
            av.w = f16_to_f32((unsigned short)(vh.y >> 16));
        }
        float4 wv = make_float4(0.f, 0.f, 0.f, 0.f);
        int gc = wcq * 4;
        if (gc < K) wv = *(const float4*)&W[(size_t)(k0 + wk) * K + gc];
        __syncthreads();
        As2[akq * 4 + 0][arow] = av.x;
        As2[akq * 4 + 1][arow] = av.y;
        As2[akq * 4 + 2][arow] = av.z;
        As2[akq * 4 + 3][arow] = av.w;
        *(float4*)&Ws2[wk][wcq * 4] = wv;
        __syncthreads();
#pragma unroll
        for (int k = 0; k < 16; ++k) {
            float4 a = *(const float4*)&As2[k][ty * 4];
            float4 wv2 = *(const float4*)&Ws2[k][tx * 4];
            acc[0][0] += a.x * wv2.x; acc[0][1] += a.x * wv2.y; acc[0][2] += a.x * wv2.z; acc[0][3] += a.x * wv2.w;
            acc[1][0] += a.y * wv2.x; acc[1][1] += a.y * wv2.y; acc[1][2] += a.y * wv2.z; acc[1][3] += a.y * wv2.w;
            acc[2][0] += a.z * wv2.x; acc[2][1] += a.z * wv2.y; acc[2][2] += a.z * wv2.z; acc[2][3] += a.z * wv2.w;
            acc[3][0] += a.w * wv2.x; acc[3][1] += a.w * wv2.y; acc[3][2] += a.w * wv2.z; acc[3][3] += a.w * wv2.w;
        }
    }
    float alv[4] = {0.f, 0.f, 0.f, 0.f}, arv[4] = {0.f, 0.f, 0.f, 0.f};
    if (tx < 4) {
#pragma unroll
        for (int c = 0; c < 4; ++c) {
            alv[c] = al2[tx * 4 + c];
            arv[c] = ar2[tx * 4 + c];
        }
    }
#pragma unroll
    for (int i = 0; i < 4; ++i) {
        int gr = r0 + ty * 4 + i;
        float pe = 0.f, pr = 0.f;
        if (tx < 4) {
#pragma unroll
            for (int c = 0; c < 4; ++c) {
                pe += acc[i][c] * alv[c];
                pr += acc[i][c] * arv[c];
            }
        }
        pe += __shfl_xor(pe, 1); pr += __shfl_xor(pr, 1);
        pe += __shfl_xor(pe, 2); pr += __shfl_xor(pr, 2);
        if (tx == 0 && gr < N) {
            el[gr] = pe;
            er[gr] = pr;
        }
        if (tx < 4 && gr < N) {
            ushort4 o4 = make_ushort4(bf16_rne(acc[i][0]), bf16_rne(acc[i][1]),
                                      bf16_rne(acc[i][2]), bf16_rne(acc[i][3]));
            *(ushort4*)&featb[(size_t)gr * 16 + tx * 4] = o4;
        }
    }
}

// ---------------- agg for H=4, D=64: wave-per-node, dwordx2 gather --------

template <int U>
__global__ __launch_bounds__(256) void agg4_kernel(const unsigned short* __restrict__ featb,
                                                   const float* __restrict__ el,
                                                   const float* __restrict__ er,
                                                   const float* __restrict__ bias,
                                                   const int* __restrict__ off,
                                                   const int* __restrict__ csr,
                                                   unsigned short* __restrict__ outh, int N) {
    constexpr int CAP = 64;
    __shared__ float s_alpha[4][4][65];  // [wave][head][edge], 65-pad
    __shared__ int s_src[4][CAP];
    int w = threadIdx.x >> 6;
    int lane = threadIdx.x & 63;
    int n = blockIdx.x * 4 + w;
    if (n >= N) return;
    int begin = off[n];
    int deg = off[n + 1] - begin;
    float4 ern = *(const float4*)&er[(size_t)n * 4];

    float m0 = -INFINITY, m1 = -INFINITY, m2 = -INFINITY, m3 = -INFINITY;
    float s0 = 0.f, s1 = 0.f, s2 = 0.f, s3 = 0.f;

    if (deg <= 64) {
        bool act = lane < deg;
        int s = 0;
        float e0 = -INFINITY, e1 = -INFINITY, e2 = -INFINITY, e3 = -INFINITY;
        if (act) {
            s = csr[begin + lane];
            float4 e = *(const float4*)&el[(size_t)s * 4];
            e0 = e.x + ern.x; e1 = e.y + ern.y; e2 = e.z + ern.z; e3 = e.w + ern.w;
            e0 = e0 > 0.f ? e0 : NEG_SLOPE * e0;
            e1 = e1 > 0.f ? e1 : NEG_SLOPE * e1;
            e2 = e2 > 0.f ? e2 : NEG_SLOPE * e2;
            e3 = e3 > 0.f ? e3 : NEG_SLOPE * e3;
        }
        m0 = e0; m1 = e1; m2 = e2; m3 = e3;
#pragma unroll
        for (int o = 32; o >= 1; o >>= 1) {
            m0 = fmaxf(m0, __shfl_xor(m0, o));
            m1 = fmaxf(m1, __shfl_xor(m1, o));
            m2 = fmaxf(m2, __shfl_xor(m2, o));
            m3 = fmaxf(m3, __shfl_xor(m3, o));
        }
        if (act) {
            s0 = __expf(e0 - m0); s1 = __expf(e1 - m1);
            s2 = __expf(e2 - m2); s3 = __expf(e3 - m3);
            s_src[w][lane] = s;
            s_alpha[w][0][lane] = s0;
            s_alpha[w][1][lane] = s1;
            s_alpha[w][2][lane] = s2;
            s_alpha[w][3][lane] = s3;
        }
#pragma unroll
        for (int o = 32; o >= 1; o >>= 1) {
            s0 += __shfl_xor(s0, o); s1 += __shfl_xor(s1, o);
            s2 += __shfl_xor(s2, o); s3 += __shfl_xor(s3, o);
        }
    } else {
        for (int i = lane; i < deg; i += 64) {
            int s = csr[begin + i];
            float4 e = *(const float4*)&el[(size_t)s * 4];
            float e0 = e.x + ern.x, e1 = e.y + ern.y, e2 = e.z + ern.z, e3 = e.w + ern.w;
            e0 = e0 > 0.f ? e0 : NEG_SLOPE * e0;
            e1 = e1 > 0.f ? e1 : NEG_SLOPE * e1;
            e2 = e2 > 0.f ? e2 : NEG_SLOPE * e2;
            e3 = e3 > 0.f ? e3 : NEG_SLOPE * e3;
            if (i < CAP) {
                s_src[w][i] = s;
                s_alpha[w][0][i] = e0; s_alpha[w][1][i] = e1;
                s_alpha[w][2][i] = e2; s_alpha[w][3][i] = e3;
            }
            m0 = fmaxf(m0, e0); m1 = fmaxf(m1, e1);
            m2 = fmaxf(m2, e2); m3 = fmaxf(m3, e3);
        }
#pragma unroll
        for (int o = 32; o >= 1; o >>= 1) {
            m0 = fmaxf(m0, __shfl_xor(m0, o));
            m1 = fmaxf(m1, __shfl_xor(m1, o));
            m2 = fmaxf(m2, __shfl_xor(m2, o));
            m3 = fmaxf(m3, __shfl_xor(m3, o));
        }
        for (int i = lane; i < deg; i += 64) {
            float e0, e1, e2, e3;
            if (i < CAP) {
                e0 = s_alpha[w][0][i]; e1 = s_alpha[w][1][i];
                e2 = s_alpha[w][2][i]; e3 = s_alpha[w][3][i];
            } else {
                int s = csr[begin + i];
                float4 e = *(const float4*)&el[(size_t)s * 4];
                e0 = e.x + ern.x; e1 = e.y + ern.y; e2 = e.z + ern.z; e3 = e.w + ern.w;
                e0 = e0 > 0.f ? e0 : NEG_SLOPE * e0;
                e1 = e1 > 0.f ? e1 : NEG_SLOPE * e1;
                e2 = e2 > 0.f ? e2 : NEG_SLOPE * e2;
                e3 = e3 > 0.f ? e3 : NEG_SLOPE * e3;
            }
            e0 = __expf(e0 - m0); e1 = __expf(e1 - m1);
            e2 = __expf(e2 - m2); e3 = __expf(e3 - m3);
            if (i < CAP) {
                s_alpha[w][0][i] = e0; s_alpha[w][1][i] = e1;
                s_alpha[w][2][i] = e2; s_alpha[w][3][i] = e3;
            }
            s0 += e0; s1 += e1; s2 += e2; s3 += e3;
        }
#pragma unroll
        for (int o = 32; o >= 1; o >>= 1) {
            s0 += __shfl_xor(s0, o); s1 += __shfl_xor(s1, o);
            s2 += __shfl_xor(s2, o); s3 += __shfl_xor(s3, o);
        }
    }

    float inv0 = deg > 0 ? 1.f / s0 : 0.f;
    float inv1 = deg > 0 ? 1.f / s1 : 0.f;
    float inv2 = deg > 0 ? 1.f / s2 : 0.f;
    float inv3 = deg > 0 ? 1.f / s3 : 0.f;

    // ---- phase 3: lane owns cols 4*lane..4*lane+3; head = lane>>4 ----
    int h = lane >> 4;
    float inv = h == 0 ? inv0 : (h == 1 ? inv1 : (h == 2 ? inv2 : inv3));
    float mh = h == 0 ? m0 : (h == 1 ? m1 : (h == 2 ? m2 : m3));
    const uint2* frow2 = (const uint2*)featb;  // row = 64 uint2 (256 bf16)
    float2 c01 = make_float2(0.f, 0.f), c23 = make_float2(0.f, 0.f);
    int dcap = deg < CAP ? deg : CAP;
    int j = 0;
    for (; j + U <= dcap; j += U) {
        int s[U];
        uint2 g[U];
        float a[U];
#pragma unroll
        for (int u = 0; u < U; ++u) s[u] = s_src[w][j + u];
#pragma unroll
        for (int u = 0; u < U; ++u) g[u] = frow2[(size_t)s[u] * 64 + lane];
#pragma unroll
        for (int u = 0; u < U; ++u) a[u] = s_alpha[w][h][j + u];
#pragma unroll
        for (int u = 0; u < U; ++u) {
            float2 a2 = make_float2(a[u], a[u]);
            float2 f01 = make_float2(__uint_as_float(g[u].x << 16),
                                     __uint_as_float(g[u].x & 0xffff0000u));
            float2 f23 = make_float2(__uint_as_float(g[u].y << 16),
                                     __uint_as_float(g[u].y & 0xffff0000u));
            c01 = fma2(a2, f01, c01);
            c23 = fma2(a2, f23, c23);
        }
    }
    for (; j < dcap; ++j) {
        int s = s_src[w][j];
        uint2 g = frow2[(size_t)s * 64 + lane];
        float a = s_alpha[w][h][j];
        float2 a2 = make_float2(a, a);
        float2 f01 = make_float2(__uint_as_float(g.x << 16),
                                 __uint_as_float(g.x & 0xffff0000u));
        float2 f23 = make_float2(__uint_as_float(g.y << 16),
                                 __uint_as_float(g.y & 0xffff0000u));
        c01 = fma2(a2, f01, c01);
        c23 = fma2(a2, f23, c23);
    }
    // spill path deg > CAP: recompute alpha for this lane's head
    for (int i = CAP; i < deg; ++i) {
        int s = csr[begin + i];
        float4 e = *(const float4*)&el[(size_t)s * 4];
        float eh = h == 0 ? e.x + ern.x : (h == 1 ? e.y + ern.y : (h == 2 ? e.z + ern.z : e.w + ern.w));
        eh = eh > 0.f ? eh : NEG_SLOPE * eh;
        float a = __expf(eh - mh);
        uint2 g = frow2[(size_t)s * 64 + lane];
        float2 a2 = make_float2(a, a);
        float2 f01 = make_float2(__uint_as_float(g.x << 16),
                                 __uint_as_float(g.x & 0xffff0000u));
        float2 f23 = make_float2(__uint_as_float(g.y << 16),
                                 __uint_as_float(g.y & 0xffff0000u));
        c01 = fma2(a2, f01, c01);
        c23 = fma2(a2, f23, c23);
    }
    float4 b4 = *(const float4*)&bias[4 * lane];
    float o0 = c01.x * inv + b4.x;
    float o1 = c01.y * inv + b4.y;
    float o2 = c23.x * inv + b4.z;
    float o3 = c23.y * inv + b4.w;
    uint2 pack;
    pack.x = (unsigned int)f16_bits(o0) | ((unsigned int)f16_bits(o1) << 16);
    pack.y = (unsigned int)f16_bits(o2) | ((unsigned int)f16_bits(o3) << 16);
    ((uint2*)outh)[(size_t)n * 64 + lane] = pack;
}

// ---------------- agg for H=1, D=16 (layer 2): 4 nodes/block --------------

template <int CAP>
__global__ __launch_bounds__(256) void agg16_kernel(const unsigned short* __restrict__ featb,
                                                    const float* __restrict__ el,
                                                    const float* __restrict__ er,
                                                    const float* __restrict__ bias,
                                                    const int* __restrict__ off,
                                                    const int* __restrict__ csr,
                                                    float* __restrict__ out, int N) {
    __shared__ float s_alpha[4][CAP];
    __shared__ int s_src[4][CAP];
    int w = threadIdx.x >> 6;
    int lane = threadIdx.x & 63;
    int n = blockIdx.x * 4 + w;
    if (n >= N) return;
    int begin = off[n];
    int deg = off[n + 1] - begin;
    float ern = er[n];

    float m = -INFINITY, ssum = 0.f;
    if (deg <= 64) {
        bool act = lane < deg;
        int s = 0;
        float e = -INFINITY;
        if (act) {
            s = csr[begin + lane];
            e = el[s] + ern;
            e = e > 0.f ? e : NEG_SLOPE * e;
        }
        m = e;
#pragma unroll
        for (int o = 32; o >= 1; o >>= 1) m = fmaxf(m, __shfl_xor(m, o));
        float x = 0.f;
        if (act) {
            x = __expf(e - m);
            s_src[w][lane] = s;
            s_alpha[w][lane] = x;
        }
        ssum = x;
#pragma unroll
        for (int o = 32; o >= 1; o >>= 1) ssum += __shfl_xor(ssum, o);
    } else {
        for (int i = lane; i < deg; i += 64) {
            int s = csr[begin + i];
            float e = el[s] + ern;
            e = e > 0.f ? e : NEG_SLOPE * e;
            if (i < CAP) { s_src[w][i] = s; s_alpha[w][i] = e; }
            m = fmaxf(m, e);
        }
#pragma unroll
        for (int o = 32; o >= 1; o >>= 1) m = fmaxf(m, __shfl_xor(m, o));
        for (int i = lane; i < deg; i += 64) {
            float e;
            if (i < CAP) e = s_alpha[w][i];
            else {
                int s = csr[begin + i];
                e = el[s] + ern;
                e = e > 0.f ? e : NEG_SLOPE * e;
            }
            float x = __expf(e - m);
            if (i < CAP) s_alpha[w][i] = x;
            ssum += x;
        }
#pragma unroll
        for (int o = 32; o >= 1; o >>= 1) ssum += __shfl_xor(ssum, o);
    }
    float inv = deg > 0 ? 1.f / ssum : 0.f;

    int slot = lane >> 3, p = lane & 7;
    int dcap = deg < CAP ? deg : CAP;
    const unsigned int* frow = (const unsigned int*)featb;
    float2 acc2 = make_float2(0.f, 0.f);
    for (int j = slot; j < dcap; j += 8) {
        int s = s_src[w][j];
        float a = s_alpha[w][j];
        unsigned int f = frow[(size_t)s * 8 + p];
        float2 f2 = make_float2(__uint_as_float(f << 16), __uint_as_float(f & 0xffff0000u));
        acc2 = fma2(make_float2(a, a), f2, acc2);
    }
    for (int i = CAP + slot; i < deg; i += 8) {
        int s = csr[begin + i];
        float e = el[s] + ern;
        e = e > 0.f ? e : NEG_SLOPE * e;
        float x = __expf(e - m);
        unsigned int f = frow[(size_t)s * 8 + p];
        float2 f2 = make_float2(__uint_as_float(f << 16), __uint_as_float(f & 0xffff0000u));
        acc2 = fma2(make_float2(x, x), f2, acc2);
    }
#pragma unroll
    for (int o = 8; o < 64; o <<= 1) {
        acc2.x += __shfl_xor(acc2.x, o);
        acc2.y += __shfl_xor(acc2.y, o);
    }
    if (lane < 8) {
        float2 o2 = make_float2(acc2.x * inv + bias[2 * p], acc2.y * inv + bias[2 * p + 1]);
        *(float2*)&out[(size_t)n * 16 + 2 * p] = o2;
    }
}

// ---------------- launch ----------------

extern "C" void kernel_launch(void* const* d_in, const int* in_sizes, int n_in,
                              void* d_out, int out_size, void* d_ws, size_t ws_size,
                              hipStream_t stream) {
    const float* inputs = (const float*)d_in[0];
    const float* W0 = (const float*)d_in[1];
    const float* al0 = (const float*)d_in[2];
    const float* ar0 = (const float*)d_in[3];
    const float* b0 = (const float*)d_in[4];
    const float* W1 = (const float*)d_in[5];
    const float* al1 = (const float*)d_in[6];
    const float* ar1 = (const float*)d_in[7];
    const float* b1 = (const float*)d_in[8];
    const float* W2 = (const float*)d_in[9];
    const float* al2 = (const float*)d_in[10];
    const float* ar2 = (const float*)d_in[11];
    const float* b2 = (const float*)d_in[12];
    const int* src = (const int*)d_in[13];
    const int* dst = (const int*)d_in[14];

    const int IN_DIM = 128;
    const int N = in_sizes[0] / IN_DIM;  // 50000
    const int E = in_sizes[13];          // 800000
    float* out = (float*)d_out;

    char* base = (char*)d_ws;
    size_t o = 0;
    auto carve = [&](size_t bytes) -> void* {
        void* p = base + o;
        o += (bytes + 255) & ~(size_t)255;
        return p;
    };
    int* off = (int*)carve((size_t)(N + 1) * sizeof(int));
    int* cursor = (int*)carve((size_t)N * sizeof(int));
    int* chunkSum = (int*)carve(64 * sizeof(int));
    int* chunkOff = (int*)carve(64 * sizeof(int));
    int* csr = (int*)carve((size_t)E * sizeof(int));
    float* el = (float*)carve((size_t)N * 4 * sizeof(float));
    float* er = (float*)carve((size_t)N * 4 * sizeof(float));
    unsigned short* featb = (unsigned short*)carve((size_t)N * 256 * sizeof(unsigned short));
    unsigned short* a0f = (unsigned short*)carve((size_t)N * 128 * sizeof(unsigned short));
    unsigned short* hbf = (unsigned short*)carve((size_t)N * 256 * sizeof(unsigned short));
    unsigned short* wt0 = (unsigned short*)carve((size_t)128 * 256 * sizeof(unsigned short));
    unsigned short* wt1 = (unsigned short*)carve((size_t)256 * 256 * sizeof(unsigned short));

    // ---- CSR build ----
    hipMemsetAsync(off, 0, (size_t)(N + 1) * sizeof(int), stream);
    int egrid = (E + 255) / 256;
    count_deg<<<egrid, 256, 0, stream>>>(dst, off, E);
    int nchunks = (N + 2047) / 2048;
    scan_chunk<<<nchunks, 256, 0, stream>>>(off, chunkSum, N);
    scan_tail<<<1, 64, 0, stream>>>(chunkSum, chunkOff, nchunks, off, N, E);
    add_chunk_off<<<(N + 255) / 256, 256, 0, stream>>>(off, cursor, chunkOff, N);
    scatter_edges<<<egrid, 256, 0, stream>>>(src, dst, cursor, csr, E);

    // ---- fused prep (inputs->f16, W0/W1->f16 transposed) ----
    int nA4 = N * 32;
    int prepTotal = nA4 + 128 * 256 + 256 * 256;
    prep_cvt<<<(prepTotal + 255) / 256, 256, 0, stream>>>(inputs, W0, W1, a0f, wt0, wt1, nA4);

    // ---- Layer 0: 128 -> 4x64 (f16 MFMA, fused elr) ----
    {
        dim3 grid(256 / 128, (N + 127) / 128);
        gemm_mfma<<<grid, 256, 0, stream>>>(a0f, wt0, featb, el, er, al0, ar0, N, 128, 256);
        agg4_kernel<8><<<(N + 3) / 4, 256, 0, stream>>>(featb, el, er, b0, off, csr, hbf, N);
    }
    // ---- Layer 1: 256 -> 4x64 (f16 MFMA, fused elr) ----
    {
        dim3 grid(256 / 128, (N + 127) / 128);
        gemm_mfma<<<grid, 256, 0, stream>>>(hbf, wt1, featb, el, er, al1, ar1, N, 256, 256);
        agg4_kernel<8><<<(N + 3) / 4, 256, 0, stream>>>(featb, el, er, b1, off, csr, hbf, N);
    }
    // ---- Layer 2: 256 -> 1x16 (fp32 GEMM from f16 A, fused elr) ----
    {
        dim3 grid(1, (N + 63) / 64);
        gemm_kernel<<<grid, 256, 0, stream>>>(hbf, W2, al2, ar2, el, er, featb, N, 256, 16);
        agg16_kernel<64><<<(N + 3) / 4, 256, 0, stream>>>(featb, el, er, b2, off, csr, out, N);
    }
}